// Round 5
// baseline (653.642 us; speedup 1.0000x reference)
//
#include <hip/hip_runtime.h>
#include <hip/hip_cooperative_groups.h>
#include <math.h>

namespace cg = cooperative_groups;

#define NN 50000
#define NE 800000
#define HD 128
#define ED 4
#define NL 4
#define MH 64
#define NE2 (NE / 2)        // 400000, MLP: 2 edges/thread
#define NBIN 196            // bin = dst >> 8 ; 49999>>8 = 195
#define BINCAP 8192         // avg 4082 edges/bin
#define CURSTRIDE 16        // pad cursors to one per 64B line
#define NBF 782             // bin_fill blocks: (NE/4 + 255)/256
#define NMLPB 1563          // MLP blocks per layer: (NE2 + 255)/256
#define GGRID 1024          // coop gather grid: 4 blocks/CU, co-residency certain

__device__ __forceinline__ float softplus_f(float a) {
    return fmaxf(a, 0.0f) + __logf(1.0f + __expf(-fabsf(a)));
}

// ---------------- fused: bin_fill (blocks 0..NBF-1) + edge MLP (rest) ----------
// 196-bin bin_fill (low scatter amplification). MLP is layer-parallel (6252
// blocks) with dual partial accumulators to break the serial fma chain.
__global__ __launch_bounds__(256) void fused_bin_mlp_kernel(
    const int* __restrict__ eidx,
    int* __restrict__ gcur,          // NBIN*CURSTRIDE ints, pre-zeroed
    int2* __restrict__ gbin,         // NBIN*BINCAP records
    const float* __restrict__ edge_attr,
    const float* __restrict__ ew1, const float* __restrict__ eb1,
    const float* __restrict__ ew2, const float* __restrict__ eb2,
    float* __restrict__ k_all)
{
    __shared__ int hist[NBIN];
    __shared__ int base[NBIN];

    if (blockIdx.x < NBF) {
        // ---- bin_fill: record int2 {src, (dloc<<20)|e}; dloc = dst&255 ----
        int tid = threadIdx.x;
        if (tid < NBIN) hist[tid] = 0;
        __syncthreads();

        int e0 = (blockIdx.x * 256 + tid) * 4;
        int bin[4], dloc[4], rank[4];
        int4 srcs, dsts;
        bool act = e0 < NE;
        if (act) {
            srcs = *reinterpret_cast<const int4*>(eidx + e0);
            dsts = *reinterpret_cast<const int4*>(eidx + NE + e0);
            int dd[4] = {dsts.x, dsts.y, dsts.z, dsts.w};
            #pragma unroll
            for (int i = 0; i < 4; ++i) {
                bin[i]  = dd[i] >> 8;
                dloc[i] = dd[i] & 255;
                rank[i] = atomicAdd(&hist[bin[i]], 1);
            }
        }
        __syncthreads();
        if (tid < NBIN && hist[tid]) base[tid] = atomicAdd(&gcur[tid * CURSTRIDE], hist[tid]);
        __syncthreads();
        if (act) {
            int ss[4] = {srcs.x, srcs.y, srcs.z, srcs.w};
            #pragma unroll
            for (int i = 0; i < 4; ++i) {
                int pos = bin[i] * BINCAP + base[bin[i]] + rank[i];
                gbin[pos] = make_int2(ss[i], (dloc[i] << 20) | (e0 + i));
            }
        }
        return;
    }

    // ---- edge MLP, one layer per block-group, 2 edges/thread, dual accs ----
    int lb = blockIdx.x - NBF;
    int l  = lb / NMLPB;
    int t  = (lb - l * NMLPB) * 256 + threadIdx.x;
    if (t >= NE2) return;
    const int e0 = t, e1 = t + NE2;
    const float4 a0 = *reinterpret_cast<const float4*>(edge_attr + (size_t)e0 * 4);
    const float4 a1 = *reinterpret_cast<const float4*>(edge_attr + (size_t)e1 * 4);

    const float* __restrict__ W0 = ew1 + (size_t)(l * ED + 0) * MH;
    const float* __restrict__ W1 = ew1 + (size_t)(l * ED + 1) * MH;
    const float* __restrict__ W2 = ew1 + (size_t)(l * ED + 2) * MH;
    const float* __restrict__ W3 = ew1 + (size_t)(l * ED + 3) * MH;
    const float* __restrict__ B1 = eb1 + (size_t)l * MH;
    const float* __restrict__ V2 = ew2 + (size_t)l * MH;

    float p0 = 0.0f, q0 = 0.0f, p1 = 0.0f, q1 = 0.0f;   // 4 independent chains
    #pragma unroll 4
    for (int j = 0; j < MH; j += 2) {
        {
            const float w0 = W0[j], w1 = W1[j], w2 = W2[j], w3 = W3[j];
            const float b1 = B1[j], v2 = V2[j];
            float m0 = fmaf(a0.x, w0, fmaf(a0.y, w1, fmaf(a0.z, w2, fmaf(a0.w, w3, b1))));
            float m1 = fmaf(a1.x, w0, fmaf(a1.y, w1, fmaf(a1.z, w2, fmaf(a1.w, w3, b1))));
            p0 = fmaf(fmaxf(m0, 0.0f), v2, p0);
            p1 = fmaf(fmaxf(m1, 0.0f), v2, p1);
        }
        {
            const float w0 = W0[j+1], w1 = W1[j+1], w2 = W2[j+1], w3 = W3[j+1];
            const float b1 = B1[j+1], v2 = V2[j+1];
            float m0 = fmaf(a0.x, w0, fmaf(a0.y, w1, fmaf(a0.z, w2, fmaf(a0.w, w3, b1))));
            float m1 = fmaf(a1.x, w0, fmaf(a1.y, w1, fmaf(a1.z, w2, fmaf(a1.w, w3, b1))));
            q0 = fmaf(fmaxf(m0, 0.0f), v2, q0);
            q1 = fmaf(fmaxf(m1, 0.0f), v2, q1);
        }
    }
    const float bb = eb2[l];
    k_all[(size_t)l * NE + e0] = softplus_f(bb + (p0 + q0));
    k_all[(size_t)l * NE + e1] = softplus_f(bb + (p1 + q1));
}

// ---------------- pass 2: per-bin exact CSR (single block per bin) ----------------
__global__ __launch_bounds__(256) void csr_build_kernel(
    const int* __restrict__ gcur,
    const int2* __restrict__ gbin,
    int2* __restrict__ gsorted,
    int2* __restrict__ nodeSD)       // {start, deg} per node
{
    __shared__ int cnt[256];
    __shared__ int cur[256];
    __shared__ int wsum[4];
    __shared__ int woff[4];
    int b = blockIdx.x;
    int tid = threadIdx.x;
    int lane = tid & 63;
    int wid = tid >> 6;
    int m = gcur[b * CURSTRIDE];
    const int2* src = gbin + (size_t)b * BINCAP;

    cnt[tid] = 0;
    __syncthreads();
    for (int p = tid; p < m; p += 256) {
        int dloc = src[p].y >> 20;
        atomicAdd(&cnt[dloc], 1);
    }
    __syncthreads();
    int v = cnt[tid];
    int x = v;
    #pragma unroll
    for (int o = 1; o < 64; o <<= 1) {
        int t = __shfl_up(x, o);
        if (lane >= o) x += t;
    }
    if (lane == 63) wsum[wid] = x;
    __syncthreads();
    if (tid == 0) {
        int a = 0;
        #pragma unroll
        for (int w = 0; w < 4; ++w) { woff[w] = a; a += wsum[w]; }
    }
    __syncthreads();
    int excl = x + woff[wid] - v;
    cur[tid] = excl;
    int n = (b << 8) + tid;
    if (n < NN) nodeSD[n] = make_int2(b * BINCAP + excl, v);
    __syncthreads();
    for (int p = tid; p < m; p += 256) {
        int2 r = src[p];
        int dloc = r.y >> 20;
        int q = atomicAdd(&cur[dloc], 1);
        gsorted[(size_t)b * BINCAP + q] = make_int2(r.x, r.y & 0xFFFFF);
    }
}

// ---------------- cooperative: all 4 gathers + head in one dispatch ------------
// Phase l reads buffer written in phase l-1 (fresh buffer each phase: x->sA->sB
// ->sC->out, so no buffer is read in two phases -> no stale-L1 hazard).
// 16 lanes per node; grid-stride over nodes; grid.sync() between phases.
__global__ __launch_bounds__(256) void coop_gather_kernel(
    const int2* __restrict__ nodeSD,
    const int2* __restrict__ gsorted,
    const float* __restrict__ k_all,
    const float* __restrict__ x,
    float* __restrict__ sA,
    float* __restrict__ sB,
    float* __restrict__ sC,
    const float* __restrict__ ew,
    const float* __restrict__ ow1,
    const float* __restrict__ b1h,
    const float* __restrict__ w2h,
    const float* __restrict__ b2h,
    float* __restrict__ out)
{
    cg::grid_group grid = cg::this_grid();

    __shared__ float su[HD], sb1[HD], sw2[HD];
    if (threadIdx.x < HD) {
        int j = threadIdx.x;
        float a = 0.0f;
        #pragma unroll 8
        for (int c = 0; c < HD; ++c) a = fmaf(ew[c], ow1[c * HD + j], a);
        su[j]  = a;
        sb1[j] = b1h[j];
        sw2[j] = w2h[j];
    }
    __syncthreads();

    const int tid   = blockIdx.x * 256 + threadIdx.x;
    const int gl    = threadIdx.x & 15;
    const int nbase = tid >> 4;
    const int nstep = (GGRID * 256) >> 4;

    // ---- phase 0: x -> sA ----
    for (int n = nbase; n < NN; n += nstep) {
        int2 sd = nodeSD[n];
        float sk = 0.0f, sks = 0.0f;
        for (int p = gl; p < sd.y; p += 16) {
            int2 r = gsorted[sd.x + p];
            float kk = k_all[r.y];
            sk += kk;
            sks = fmaf(kk, x[r.x], sks);
        }
        #pragma unroll
        for (int m = 1; m < 16; m <<= 1) { sk += __shfl_xor(sk, m); sks += __shfl_xor(sks, m); }
        if (gl == 0) sA[n] = fmaf(-sk, x[n], sks);
    }
    __threadfence();
    grid.sync();

    // ---- phase 1: sA -> sB ----
    for (int n = nbase; n < NN; n += nstep) {
        int2 sd = nodeSD[n];
        float sk = 0.0f, sks = 0.0f;
        for (int p = gl; p < sd.y; p += 16) {
            int2 r = gsorted[sd.x + p];
            float kk = k_all[(size_t)NE + r.y];
            sk += kk;
            sks = fmaf(kk, sA[r.x], sks);
        }
        #pragma unroll
        for (int m = 1; m < 16; m <<= 1) { sk += __shfl_xor(sk, m); sks += __shfl_xor(sks, m); }
        if (gl == 0) sB[n] = fmaf(-sk, sA[n], sks);
    }
    __threadfence();
    grid.sync();

    // ---- phase 2: sB -> sC ----
    for (int n = nbase; n < NN; n += nstep) {
        int2 sd = nodeSD[n];
        float sk = 0.0f, sks = 0.0f;
        for (int p = gl; p < sd.y; p += 16) {
            int2 r = gsorted[sd.x + p];
            float kk = k_all[2 * (size_t)NE + r.y];
            sk += kk;
            sks = fmaf(kk, sB[r.x], sks);
        }
        #pragma unroll
        for (int m = 1; m < 16; m <<= 1) { sk += __shfl_xor(sk, m); sks += __shfl_xor(sks, m); }
        if (gl == 0) sC[n] = fmaf(-sk, sB[n], sks);
    }
    __threadfence();
    grid.sync();

    // ---- phase 3 + head: sC -> out ----
    for (int n = nbase; n < NN; n += nstep) {
        int2 sd = nodeSD[n];
        float sk = 0.0f, sks = 0.0f;
        for (int p = gl; p < sd.y; p += 16) {
            int2 r = gsorted[sd.x + p];
            float kk = k_all[3 * (size_t)NE + r.y];
            sk += kk;
            sks = fmaf(kk, sC[r.x], sks);
        }
        #pragma unroll
        for (int m = 1; m < 16; m <<= 1) { sk += __shfl_xor(sk, m); sks += __shfl_xor(sks, m); }
        float sv = fmaf(-sk, sC[n], sks);   // all 16 lanes hold sv

        float acc = 0.0f;
        #pragma unroll
        for (int jj = 0; jj < 8; ++jj) {
            int j = gl + jj * 16;
            acc = fmaf(fmaxf(fmaf(sv, su[j], sb1[j]), 0.0f), sw2[j], acc);
        }
        #pragma unroll
        for (int m = 1; m < 16; m <<= 1) acc += __shfl_xor(acc, m);
        if (gl == 0) out[n] = acc + b2h[0];
    }
}

// ---------------- launch ----------------

extern "C" void kernel_launch(void* const* d_in, const int* in_sizes, int n_in,
                              void* d_out, int out_size, void* d_ws, size_t ws_size,
                              hipStream_t stream) {
    const float* x        = (const float*)d_in[0];
    const int*   eidx     = (const int*)d_in[1];
    const float* edge_attr= (const float*)d_in[2];
    const float* embed_w  = (const float*)d_in[3];
    // d_in[4] = embed_b (cancels in the message; unused)
    const float* ew1      = (const float*)d_in[5];
    const float* eb1      = (const float*)d_in[6];
    const float* ew2      = (const float*)d_in[7];
    const float* eb2      = (const float*)d_in[8];
    const float* ow1      = (const float*)d_in[9];
    const float* ob1      = (const float*)d_in[10];
    const float* ow2      = (const float*)d_in[11];
    const float* ob2      = (const float*)d_in[12];
    float* out = (float*)d_out;

    char* ws = (char*)d_ws;
    const size_t kbytes  = (size_t)NL * NE * sizeof(float);            // 12.8 MB
    const size_t gbbytes = (size_t)NBIN * BINCAP * sizeof(int2);       // 12.85 MB
    const size_t curbyte = (size_t)NBIN * CURSTRIDE * sizeof(int);     // 12.5 KB
    const size_t sdbytes = (size_t)NN * sizeof(int2);                  // 400 KB
    const size_t sbytes  = (size_t)NN * sizeof(float);                 // 200 KB

    size_t off = 0;
    float* k_all   = (float*)(ws + off); off += kbytes;
    int2*  gbin    = (int2*) (ws + off); off += gbbytes;
    int2*  gsorted = (int2*) (ws + off); off += gbbytes;
    int*   gcur    = (int*)  (ws + off); off += curbyte;
    int2*  nodeSD  = (int2*) (ws + off); off += sdbytes;
    float* sA      = (float*)(ws + off); off += sbytes;
    float* sB      = (float*)(ws + off); off += sbytes;
    float* sC      = (float*)gbin;       // gbin is dead after csr_build

    hipMemsetAsync(gcur, 0, curbyte, stream);

    fused_bin_mlp_kernel<<<NBF + NL * NMLPB, 256, 0, stream>>>(
        eidx, gcur, gbin, edge_attr, ew1, eb1, ew2, eb2, k_all);

    csr_build_kernel<<<NBIN, 256, 0, stream>>>(gcur, gbin, gsorted, nodeSD);

    void* args[] = { (void*)&nodeSD, (void*)&gsorted, (void*)&k_all, (void*)&x,
                     (void*)&sA, (void*)&sB, (void*)&sC,
                     (void*)&embed_w, (void*)&ow1, (void*)&ob1, (void*)&ow2,
                     (void*)&ob2, (void*)&out };
    hipLaunchCooperativeKernel((const void*)coop_gather_kernel,
                               dim3(GGRID), dim3(256), args, 0, stream);
}

// Round 6
// 127.472 us; speedup vs baseline: 5.1277x; 5.1277x over previous
//
#include <hip/hip_runtime.h>
#include <math.h>

#define NN 50000
#define NE 800000
#define HD 128
#define ED 4
#define NL 4
#define MH 64
#define NE2 (NE / 2)        // 400000, MLP: 2 edges/thread
#define NBIN 196            // bin = dst >> 8 ; 49999>>8 = 195
#define BINCAP 8192         // avg 4082 edges/bin
#define CURSTRIDE 16        // pad cursors to one per 64B line
#define NBF 782             // bin_fill blocks: (NE/4 + 255)/256
#define NMLPB 1563          // MLP blocks per layer: (NE2 + 255)/256

__device__ __forceinline__ float softplus_f(float a) {
    return fmaxf(a, 0.0f) + __logf(1.0f + __expf(-fabsf(a)));
}

// ---------------- fused: bin_fill (blocks 0..NBF-1) + edge MLP (rest) ----------
// 196-bin bin_fill (low scatter amplification). MLP is layer-parallel (6252
// blocks) with dual partial accumulators to break the serial fma chain.
// Round-5 data: this front-end (memset+this+csr) = ~55 us vs round-0's ~72.
__global__ __launch_bounds__(256) void fused_bin_mlp_kernel(
    const int* __restrict__ eidx,
    int* __restrict__ gcur,          // NBIN*CURSTRIDE ints, pre-zeroed
    int2* __restrict__ gbin,         // NBIN*BINCAP records
    const float* __restrict__ edge_attr,
    const float* __restrict__ ew1, const float* __restrict__ eb1,
    const float* __restrict__ ew2, const float* __restrict__ eb2,
    float* __restrict__ k_all)
{
    __shared__ int hist[NBIN];
    __shared__ int base[NBIN];

    if (blockIdx.x < NBF) {
        // ---- bin_fill: record int2 {src, (dloc<<20)|e}; dloc = dst&255 ----
        int tid = threadIdx.x;
        if (tid < NBIN) hist[tid] = 0;
        __syncthreads();

        int e0 = (blockIdx.x * 256 + tid) * 4;
        int bin[4], dloc[4], rank[4];
        int4 srcs, dsts;
        bool act = e0 < NE;
        if (act) {
            srcs = *reinterpret_cast<const int4*>(eidx + e0);
            dsts = *reinterpret_cast<const int4*>(eidx + NE + e0);
            int dd[4] = {dsts.x, dsts.y, dsts.z, dsts.w};
            #pragma unroll
            for (int i = 0; i < 4; ++i) {
                bin[i]  = dd[i] >> 8;
                dloc[i] = dd[i] & 255;
                rank[i] = atomicAdd(&hist[bin[i]], 1);
            }
        }
        __syncthreads();
        if (tid < NBIN && hist[tid]) base[tid] = atomicAdd(&gcur[tid * CURSTRIDE], hist[tid]);
        __syncthreads();
        if (act) {
            int ss[4] = {srcs.x, srcs.y, srcs.z, srcs.w};
            #pragma unroll
            for (int i = 0; i < 4; ++i) {
                int pos = bin[i] * BINCAP + base[bin[i]] + rank[i];
                gbin[pos] = make_int2(ss[i], (dloc[i] << 20) | (e0 + i));
            }
        }
        return;
    }

    // ---- edge MLP, one layer per block-group, 2 edges/thread, dual accs ----
    int lb = blockIdx.x - NBF;
    int l  = lb / NMLPB;
    int t  = (lb - l * NMLPB) * 256 + threadIdx.x;
    if (t >= NE2) return;
    const int e0 = t, e1 = t + NE2;
    const float4 a0 = *reinterpret_cast<const float4*>(edge_attr + (size_t)e0 * 4);
    const float4 a1 = *reinterpret_cast<const float4*>(edge_attr + (size_t)e1 * 4);

    const float* __restrict__ W0 = ew1 + (size_t)(l * ED + 0) * MH;
    const float* __restrict__ W1 = ew1 + (size_t)(l * ED + 1) * MH;
    const float* __restrict__ W2 = ew1 + (size_t)(l * ED + 2) * MH;
    const float* __restrict__ W3 = ew1 + (size_t)(l * ED + 3) * MH;
    const float* __restrict__ B1 = eb1 + (size_t)l * MH;
    const float* __restrict__ V2 = ew2 + (size_t)l * MH;

    float p0 = 0.0f, q0 = 0.0f, p1 = 0.0f, q1 = 0.0f;   // 4 independent chains
    #pragma unroll 4
    for (int j = 0; j < MH; j += 2) {
        {
            const float w0 = W0[j], w1 = W1[j], w2 = W2[j], w3 = W3[j];
            const float b1 = B1[j], v2 = V2[j];
            float m0 = fmaf(a0.x, w0, fmaf(a0.y, w1, fmaf(a0.z, w2, fmaf(a0.w, w3, b1))));
            float m1 = fmaf(a1.x, w0, fmaf(a1.y, w1, fmaf(a1.z, w2, fmaf(a1.w, w3, b1))));
            p0 = fmaf(fmaxf(m0, 0.0f), v2, p0);
            p1 = fmaf(fmaxf(m1, 0.0f), v2, p1);
        }
        {
            const float w0 = W0[j+1], w1 = W1[j+1], w2 = W2[j+1], w3 = W3[j+1];
            const float b1 = B1[j+1], v2 = V2[j+1];
            float m0 = fmaf(a0.x, w0, fmaf(a0.y, w1, fmaf(a0.z, w2, fmaf(a0.w, w3, b1))));
            float m1 = fmaf(a1.x, w0, fmaf(a1.y, w1, fmaf(a1.z, w2, fmaf(a1.w, w3, b1))));
            q0 = fmaf(fmaxf(m0, 0.0f), v2, q0);
            q1 = fmaf(fmaxf(m1, 0.0f), v2, q1);
        }
    }
    const float bb = eb2[l];
    k_all[(size_t)l * NE + e0] = softplus_f(bb + (p0 + q0));
    k_all[(size_t)l * NE + e1] = softplus_f(bb + (p1 + q1));
}

// ---------------- pass 2: per-bin exact CSR (single block per bin) ----------------
__global__ __launch_bounds__(256) void csr_build_kernel(
    const int* __restrict__ gcur,
    const int2* __restrict__ gbin,
    int2* __restrict__ gsorted,
    int2* __restrict__ nodeSD)       // {start, deg} per node
{
    __shared__ int cnt[256];
    __shared__ int cur[256];
    __shared__ int wsum[4];
    __shared__ int woff[4];
    int b = blockIdx.x;
    int tid = threadIdx.x;
    int lane = tid & 63;
    int wid = tid >> 6;
    int m = gcur[b * CURSTRIDE];
    const int2* src = gbin + (size_t)b * BINCAP;

    cnt[tid] = 0;
    __syncthreads();
    for (int p = tid; p < m; p += 256) {
        int dloc = src[p].y >> 20;
        atomicAdd(&cnt[dloc], 1);
    }
    __syncthreads();
    int v = cnt[tid];
    int x = v;
    #pragma unroll
    for (int o = 1; o < 64; o <<= 1) {
        int t = __shfl_up(x, o);
        if (lane >= o) x += t;
    }
    if (lane == 63) wsum[wid] = x;
    __syncthreads();
    if (tid == 0) {
        int a = 0;
        #pragma unroll
        for (int w = 0; w < 4; ++w) { woff[w] = a; a += wsum[w]; }
    }
    __syncthreads();
    int excl = x + woff[wid] - v;
    cur[tid] = excl;
    int n = (b << 8) + tid;
    if (n < NN) nodeSD[n] = make_int2(b * BINCAP + excl, v);
    __syncthreads();
    for (int p = tid; p < m; p += 256) {
        int2 r = src[p];
        int dloc = r.y >> 20;
        int q = atomicAdd(&cur[dloc], 1);
        gsorted[(size_t)b * BINCAP + q] = make_int2(r.x, r.y & 0xFFFFF);
    }
}

// ---------------- per-layer gather (no atomics) ----------------
// rank-1 collapse: h_l[n,c] = s_l[n]*ew[c]; s_0 = x.
// s_out[n] = sum_p k_p*s_in[src_p] - (sum_p k_p)*s_in[n]; 16 lanes per node.
__global__ void sgather_kernel(const int2* __restrict__ nodeSD,
                               const int2* __restrict__ gsorted,
                               const float* __restrict__ k_all,
                               int l,
                               const float* __restrict__ s_in,
                               float* __restrict__ s_out) {
    int t = blockIdx.x * 256 + threadIdx.x;
    int n = t >> 4;
    int gl = threadIdx.x & 15;
    if (n >= NN) return;
    int2 sd = nodeSD[n];
    float sk = 0.0f, sks = 0.0f;
    for (int p = gl; p < sd.y; p += 16) {
        int2 r = gsorted[sd.x + p];
        float kk = k_all[(size_t)l * NE + r.y];
        sk += kk;
        sks = fmaf(kk, s_in[r.x], sks);
    }
    #pragma unroll
    for (int m = 1; m < 16; m <<= 1) {
        sk  += __shfl_xor(sk, m);
        sks += __shfl_xor(sks, m);
    }
    if (gl == 0) s_out[n] = fmaf(-sk, s_in[n], sks);
}

// ---------------- layer-3 gather fused with the output head ----------------
__global__ void sgather_head_kernel(const int2* __restrict__ nodeSD,
                                    const int2* __restrict__ gsorted,
                                    const float* __restrict__ k_all,
                                    const float* __restrict__ s_in,
                                    const float* __restrict__ ew,
                                    const float* __restrict__ ow1,
                                    const float* __restrict__ b1,
                                    const float* __restrict__ w2,
                                    const float* __restrict__ b2,
                                    float* __restrict__ out) {
    __shared__ float su[HD], sb1[HD], sw2[HD];
    if (threadIdx.x < HD) {
        int j = threadIdx.x;
        float a = 0.0f;
        #pragma unroll 8
        for (int c = 0; c < HD; ++c) a = fmaf(ew[c], ow1[c * HD + j], a);
        su[j]  = a;
        sb1[j] = b1[j];
        sw2[j] = w2[j];
    }
    __syncthreads();

    int t = blockIdx.x * 256 + threadIdx.x;
    int n = t >> 4;
    int gl = threadIdx.x & 15;
    if (n >= NN) return;
    int2 sd = nodeSD[n];
    float sk = 0.0f, sks = 0.0f;
    for (int p = gl; p < sd.y; p += 16) {
        int2 r = gsorted[sd.x + p];
        float kk = k_all[3 * (size_t)NE + r.y];
        sk += kk;
        sks = fmaf(kk, s_in[r.x], sks);
    }
    #pragma unroll
    for (int m = 1; m < 16; m <<= 1) {
        sk  += __shfl_xor(sk, m);
        sks += __shfl_xor(sks, m);
    }
    float sv = fmaf(-sk, s_in[n], sks);   // all 16 lanes hold sv

    float acc = 0.0f;
    #pragma unroll
    for (int jj = 0; jj < 8; ++jj) {
        int j = gl + jj * 16;
        acc = fmaf(fmaxf(fmaf(sv, su[j], sb1[j]), 0.0f), sw2[j], acc);
    }
    #pragma unroll
    for (int m = 1; m < 16; m <<= 1) acc += __shfl_xor(acc, m);
    if (gl == 0) out[n] = acc + b2[0];
}

// ---------------- launch ----------------

extern "C" void kernel_launch(void* const* d_in, const int* in_sizes, int n_in,
                              void* d_out, int out_size, void* d_ws, size_t ws_size,
                              hipStream_t stream) {
    const float* x        = (const float*)d_in[0];
    const int*   eidx     = (const int*)d_in[1];
    const float* edge_attr= (const float*)d_in[2];
    const float* embed_w  = (const float*)d_in[3];
    // d_in[4] = embed_b (cancels in the message; unused)
    const float* ew1      = (const float*)d_in[5];
    const float* eb1      = (const float*)d_in[6];
    const float* ew2      = (const float*)d_in[7];
    const float* eb2      = (const float*)d_in[8];
    const float* ow1      = (const float*)d_in[9];
    const float* ob1      = (const float*)d_in[10];
    const float* ow2      = (const float*)d_in[11];
    const float* ob2      = (const float*)d_in[12];
    float* out = (float*)d_out;

    char* ws = (char*)d_ws;
    const size_t kbytes  = (size_t)NL * NE * sizeof(float);            // 12.8 MB
    const size_t gbbytes = (size_t)NBIN * BINCAP * sizeof(int2);       // 12.85 MB
    const size_t curbyte = (size_t)NBIN * CURSTRIDE * sizeof(int);     // 12.5 KB
    const size_t sdbytes = (size_t)NN * sizeof(int2);                  // 400 KB
    const size_t sbytes  = (size_t)NN * sizeof(float);                 // 200 KB

    size_t off = 0;
    float* k_all   = (float*)(ws + off); off += kbytes;
    int2*  gbin    = (int2*) (ws + off); off += gbbytes;
    int2*  gsorted = (int2*) (ws + off); off += gbbytes;
    int*   gcur    = (int*)  (ws + off); off += curbyte;
    int2*  nodeSD  = (int2*) (ws + off); off += sdbytes;
    float* sA      = (float*)(ws + off); off += sbytes;
    float* sB      = (float*)(ws + off); off += sbytes;

    hipMemsetAsync(gcur, 0, curbyte, stream);

    fused_bin_mlp_kernel<<<NBF + NL * NMLPB, 256, 0, stream>>>(
        eidx, gcur, gbin, edge_attr, ew1, eb1, ew2, eb2, k_all);

    csr_build_kernel<<<NBIN, 256, 0, stream>>>(gcur, gbin, gsorted, nodeSD);

    const int ggrid = (NN * 16 + 255) / 256;
    sgather_kernel<<<ggrid, 256, 0, stream>>>(nodeSD, gsorted, k_all, 0, x,  sA);
    sgather_kernel<<<ggrid, 256, 0, stream>>>(nodeSD, gsorted, k_all, 1, sA, sB);
    sgather_kernel<<<ggrid, 256, 0, stream>>>(nodeSD, gsorted, k_all, 2, sB, sA);
    sgather_head_kernel<<<ggrid, 256, 0, stream>>>(nodeSD, gsorted, k_all, sA,
                                                   embed_w, ow1, ob1, ow2, ob2, out);
}

// Round 7
// 121.797 us; speedup vs baseline: 5.3667x; 1.0466x over previous
//
#include <hip/hip_runtime.h>
#include <math.h>

#define NN 50000
#define NE 800000
#define HD 128
#define ED 4
#define NL 4
#define MH 64
#define NE2 (NE / 2)        // 400000, MLP: 2 edges/thread
#define NBIN 196            // bin = dst >> 8 ; 49999>>8 = 195
#define BINCAP 8192         // avg 4082 edges/bin
#define CURSTRIDE 16        // pad cursors to one per 64B line
#define NBF 782             // bin_fill blocks: (NE/4 + 255)/256
#define NMLPB 1563          // MLP blocks per layer: (NE2 + 255)/256

__device__ __forceinline__ float softplus_f(float a) {
    return fmaxf(a, 0.0f) + __logf(1.0f + __expf(-fabsf(a)));
}

// ---- edge MLP for one layer, 2 edges/thread, dual partial accumulators ----
__device__ __forceinline__ void mlp_layer(
    int l, int t,
    const float* __restrict__ edge_attr,
    const float* __restrict__ ew1, const float* __restrict__ eb1,
    const float* __restrict__ ew2, const float* __restrict__ eb2,
    float* __restrict__ k_all)
{
    if (t >= NE2) return;
    const int e0 = t, e1 = t + NE2;
    const float4 a0 = *reinterpret_cast<const float4*>(edge_attr + (size_t)e0 * 4);
    const float4 a1 = *reinterpret_cast<const float4*>(edge_attr + (size_t)e1 * 4);

    const float* __restrict__ W0 = ew1 + (size_t)(l * ED + 0) * MH;
    const float* __restrict__ W1 = ew1 + (size_t)(l * ED + 1) * MH;
    const float* __restrict__ W2 = ew1 + (size_t)(l * ED + 2) * MH;
    const float* __restrict__ W3 = ew1 + (size_t)(l * ED + 3) * MH;
    const float* __restrict__ B1 = eb1 + (size_t)l * MH;
    const float* __restrict__ V2 = ew2 + (size_t)l * MH;

    float p0 = 0.0f, q0 = 0.0f, p1 = 0.0f, q1 = 0.0f;   // 4 independent chains
    #pragma unroll 4
    for (int j = 0; j < MH; j += 2) {
        {
            const float w0 = W0[j], w1 = W1[j], w2 = W2[j], w3 = W3[j];
            const float b1 = B1[j], v2 = V2[j];
            float m0 = fmaf(a0.x, w0, fmaf(a0.y, w1, fmaf(a0.z, w2, fmaf(a0.w, w3, b1))));
            float m1 = fmaf(a1.x, w0, fmaf(a1.y, w1, fmaf(a1.z, w2, fmaf(a1.w, w3, b1))));
            p0 = fmaf(fmaxf(m0, 0.0f), v2, p0);
            p1 = fmaf(fmaxf(m1, 0.0f), v2, p1);
        }
        {
            const float w0 = W0[j+1], w1 = W1[j+1], w2 = W2[j+1], w3 = W3[j+1];
            const float b1 = B1[j+1], v2 = V2[j+1];
            float m0 = fmaf(a0.x, w0, fmaf(a0.y, w1, fmaf(a0.z, w2, fmaf(a0.w, w3, b1))));
            float m1 = fmaf(a1.x, w0, fmaf(a1.y, w1, fmaf(a1.z, w2, fmaf(a1.w, w3, b1))));
            q0 = fmaf(fmaxf(m0, 0.0f), v2, q0);
            q1 = fmaf(fmaxf(m1, 0.0f), v2, q1);
        }
    }
    const float bb = eb2[l];
    k_all[(size_t)l * NE + e0] = softplus_f(bb + (p0 + q0));
    k_all[(size_t)l * NE + e1] = softplus_f(bb + (p1 + q1));
}

// ---------------- dispatch A: bin_fill (blocks 0..NBF-1) || MLP layer 0 --------
__global__ __launch_bounds__(256) void fill_mlp0_kernel(
    const int* __restrict__ eidx,
    int* __restrict__ gcur,          // NBIN*CURSTRIDE ints, pre-zeroed
    int2* __restrict__ gbin,         // NBIN*BINCAP records
    const float* __restrict__ edge_attr,
    const float* __restrict__ ew1, const float* __restrict__ eb1,
    const float* __restrict__ ew2, const float* __restrict__ eb2,
    float* __restrict__ k_all)
{
    __shared__ int hist[NBIN];
    __shared__ int base[NBIN];

    if (blockIdx.x < NBF) {
        // ---- bin_fill: record int2 {src, (dloc<<20)|e}; dloc = dst&255 ----
        int tid = threadIdx.x;
        if (tid < NBIN) hist[tid] = 0;
        __syncthreads();

        int e0 = (blockIdx.x * 256 + tid) * 4;
        int bin[4], dloc[4], rank[4];
        int4 srcs, dsts;
        bool act = e0 < NE;
        if (act) {
            srcs = *reinterpret_cast<const int4*>(eidx + e0);
            dsts = *reinterpret_cast<const int4*>(eidx + NE + e0);
            int dd[4] = {dsts.x, dsts.y, dsts.z, dsts.w};
            #pragma unroll
            for (int i = 0; i < 4; ++i) {
                bin[i]  = dd[i] >> 8;
                dloc[i] = dd[i] & 255;
                rank[i] = atomicAdd(&hist[bin[i]], 1);
            }
        }
        __syncthreads();
        if (tid < NBIN && hist[tid]) base[tid] = atomicAdd(&gcur[tid * CURSTRIDE], hist[tid]);
        __syncthreads();
        if (act) {
            int ss[4] = {srcs.x, srcs.y, srcs.z, srcs.w};
            #pragma unroll
            for (int i = 0; i < 4; ++i) {
                int pos = bin[i] * BINCAP + base[bin[i]] + rank[i];
                gbin[pos] = make_int2(ss[i], (dloc[i] << 20) | (e0 + i));
            }
        }
        return;
    }

    int t = (blockIdx.x - NBF) * 256 + threadIdx.x;
    mlp_layer(0, t, edge_attr, ew1, eb1, ew2, eb2, k_all);
}

// ---------------- dispatch B: csr_build (blocks 0..NBIN-1) || MLP layers 1-3 ---
// csr's 196 low-occupancy blocks are scheduled first and their latency hides
// under the 4689 MLP blocks' VALU work (DAG-independent stages).
__global__ __launch_bounds__(256) void csr_mlp123_kernel(
    const int* __restrict__ gcur,
    const int2* __restrict__ gbin,
    int2* __restrict__ gsorted,
    int2* __restrict__ nodeSD,       // {start, deg} per node
    const float* __restrict__ edge_attr,
    const float* __restrict__ ew1, const float* __restrict__ eb1,
    const float* __restrict__ ew2, const float* __restrict__ eb2,
    float* __restrict__ k_all)
{
    __shared__ int cnt[256];
    __shared__ int cur[256];
    __shared__ int wsum[4];
    __shared__ int woff[4];

    if (blockIdx.x < NBIN) {
        int b = blockIdx.x;
        int tid = threadIdx.x;
        int lane = tid & 63;
        int wid = tid >> 6;
        int m = gcur[b * CURSTRIDE];
        const int2* src = gbin + (size_t)b * BINCAP;

        cnt[tid] = 0;
        __syncthreads();
        for (int p = tid; p < m; p += 256) {
            int dloc = src[p].y >> 20;
            atomicAdd(&cnt[dloc], 1);
        }
        __syncthreads();
        int v = cnt[tid];
        int x = v;
        #pragma unroll
        for (int o = 1; o < 64; o <<= 1) {
            int t = __shfl_up(x, o);
            if (lane >= o) x += t;
        }
        if (lane == 63) wsum[wid] = x;
        __syncthreads();
        if (tid == 0) {
            int a = 0;
            #pragma unroll
            for (int w = 0; w < 4; ++w) { woff[w] = a; a += wsum[w]; }
        }
        __syncthreads();
        int excl = x + woff[wid] - v;
        cur[tid] = excl;
        int n = (b << 8) + tid;
        if (n < NN) nodeSD[n] = make_int2(b * BINCAP + excl, v);
        __syncthreads();
        for (int p = tid; p < m; p += 256) {
            int2 r = src[p];
            int dloc = r.y >> 20;
            int q = atomicAdd(&cur[dloc], 1);
            gsorted[(size_t)b * BINCAP + q] = make_int2(r.x, r.y & 0xFFFFF);
        }
        return;
    }

    int lb = blockIdx.x - NBIN;
    int l  = 1 + lb / NMLPB;
    int t  = (lb - (l - 1) * NMLPB) * 256 + threadIdx.x;
    mlp_layer(l, t, edge_attr, ew1, eb1, ew2, eb2, k_all);
}

// ---------------- per-layer gather (no atomics) ----------------
// rank-1 collapse: h_l[n,c] = s_l[n]*ew[c]; s_0 = x.
// s_out[n] = sum_p k_p*s_in[src_p] - (sum_p k_p)*s_in[n]; 16 lanes per node.
__global__ void sgather_kernel(const int2* __restrict__ nodeSD,
                               const int2* __restrict__ gsorted,
                               const float* __restrict__ k_all,
                               int l,
                               const float* __restrict__ s_in,
                               float* __restrict__ s_out) {
    int t = blockIdx.x * 256 + threadIdx.x;
    int n = t >> 4;
    int gl = threadIdx.x & 15;
    if (n >= NN) return;
    int2 sd = nodeSD[n];
    float sk = 0.0f, sks = 0.0f;
    for (int p = gl; p < sd.y; p += 16) {
        int2 r = gsorted[sd.x + p];
        float kk = k_all[(size_t)l * NE + r.y];
        sk += kk;
        sks = fmaf(kk, s_in[r.x], sks);
    }
    #pragma unroll
    for (int m = 1; m < 16; m <<= 1) {
        sk  += __shfl_xor(sk, m);
        sks += __shfl_xor(sks, m);
    }
    if (gl == 0) s_out[n] = fmaf(-sk, s_in[n], sks);
}

// ---------------- layer-3 gather fused with the output head ----------------
__global__ void sgather_head_kernel(const int2* __restrict__ nodeSD,
                                    const int2* __restrict__ gsorted,
                                    const float* __restrict__ k_all,
                                    const float* __restrict__ s_in,
                                    const float* __restrict__ ew,
                                    const float* __restrict__ ow1,
                                    const float* __restrict__ b1,
                                    const float* __restrict__ w2,
                                    const float* __restrict__ b2,
                                    float* __restrict__ out) {
    __shared__ float su[HD], sb1[HD], sw2[HD];
    if (threadIdx.x < HD) {
        int j = threadIdx.x;
        float a = 0.0f;
        #pragma unroll 8
        for (int c = 0; c < HD; ++c) a = fmaf(ew[c], ow1[c * HD + j], a);
        su[j]  = a;
        sb1[j] = b1[j];
        sw2[j] = w2[j];
    }
    __syncthreads();

    int t = blockIdx.x * 256 + threadIdx.x;
    int n = t >> 4;
    int gl = threadIdx.x & 15;
    if (n >= NN) return;
    int2 sd = nodeSD[n];
    float sk = 0.0f, sks = 0.0f;
    for (int p = gl; p < sd.y; p += 16) {
        int2 r = gsorted[sd.x + p];
        float kk = k_all[3 * (size_t)NE + r.y];
        sk += kk;
        sks = fmaf(kk, s_in[r.x], sks);
    }
    #pragma unroll
    for (int m = 1; m < 16; m <<= 1) {
        sk  += __shfl_xor(sk, m);
        sks += __shfl_xor(sks, m);
    }
    float sv = fmaf(-sk, s_in[n], sks);   // all 16 lanes hold sv

    float acc = 0.0f;
    #pragma unroll
    for (int jj = 0; jj < 8; ++jj) {
        int j = gl + jj * 16;
        acc = fmaf(fmaxf(fmaf(sv, su[j], sb1[j]), 0.0f), sw2[j], acc);
    }
    #pragma unroll
    for (int m = 1; m < 16; m <<= 1) acc += __shfl_xor(acc, m);
    if (gl == 0) out[n] = acc + b2[0];
}

// ---------------- launch ----------------

extern "C" void kernel_launch(void* const* d_in, const int* in_sizes, int n_in,
                              void* d_out, int out_size, void* d_ws, size_t ws_size,
                              hipStream_t stream) {
    const float* x        = (const float*)d_in[0];
    const int*   eidx     = (const int*)d_in[1];
    const float* edge_attr= (const float*)d_in[2];
    const float* embed_w  = (const float*)d_in[3];
    // d_in[4] = embed_b (cancels in the message; unused)
    const float* ew1      = (const float*)d_in[5];
    const float* eb1      = (const float*)d_in[6];
    const float* ew2      = (const float*)d_in[7];
    const float* eb2      = (const float*)d_in[8];
    const float* ow1      = (const float*)d_in[9];
    const float* ob1      = (const float*)d_in[10];
    const float* ow2      = (const float*)d_in[11];
    const float* ob2      = (const float*)d_in[12];
    float* out = (float*)d_out;

    char* ws = (char*)d_ws;
    const size_t kbytes  = (size_t)NL * NE * sizeof(float);            // 12.8 MB
    const size_t gbbytes = (size_t)NBIN * BINCAP * sizeof(int2);       // 12.85 MB
    const size_t curbyte = (size_t)NBIN * CURSTRIDE * sizeof(int);     // 12.5 KB
    const size_t sdbytes = (size_t)NN * sizeof(int2);                  // 400 KB
    const size_t sbytes  = (size_t)NN * sizeof(float);                 // 200 KB

    size_t off = 0;
    float* k_all   = (float*)(ws + off); off += kbytes;
    int2*  gbin    = (int2*) (ws + off); off += gbbytes;
    int2*  gsorted = (int2*) (ws + off); off += gbbytes;
    int*   gcur    = (int*)  (ws + off); off += curbyte;
    int2*  nodeSD  = (int2*) (ws + off); off += sdbytes;
    float* sA      = (float*)(ws + off); off += sbytes;
    float* sB      = (float*)(ws + off); off += sbytes;

    hipMemsetAsync(gcur, 0, curbyte, stream);

    fill_mlp0_kernel<<<NBF + NMLPB, 256, 0, stream>>>(
        eidx, gcur, gbin, edge_attr, ew1, eb1, ew2, eb2, k_all);

    csr_mlp123_kernel<<<NBIN + 3 * NMLPB, 256, 0, stream>>>(
        gcur, gbin, gsorted, nodeSD, edge_attr, ew1, eb1, ew2, eb2, k_all);

    const int ggrid = (NN * 16 + 255) / 256;
    sgather_kernel<<<ggrid, 256, 0, stream>>>(nodeSD, gsorted, k_all, 0, x,  sA);
    sgather_kernel<<<ggrid, 256, 0, stream>>>(nodeSD, gsorted, k_all, 1, sA, sB);
    sgather_kernel<<<ggrid, 256, 0, stream>>>(nodeSD, gsorted, k_all, 2, sB, sA);
    sgather_head_kernel<<<ggrid, 256, 0, stream>>>(nodeSD, gsorted, k_all, sA,
                                                   embed_w, ow1, ob1, ow2, ob2, out);
}